// Round 12
// baseline (119.884 us; speedup 1.0000x reference)
//
#include <hip/hip_runtime.h>

// CRF forward (log-partition), SEQ=512, BATCH=1024, TAGS=32, fp32 in/out.
//
// R21: raise outstanding bytes (Little's law). Invariant across R17-R20:
// chunk period ~3200cy regardless of chunk bytes (33->16.5KB), CU count
// (64->128), consumer pipelining, barrier style; and R17 vs R19 proved the
// consumer has slack. Model that fits: delivered BW = inflight/latency with
// inflight pinned at ~3.4MB total (<=3 FILL bursts/block; R18 64x27KB ==
// R20 128x13.5KB - why both rounds tied). Fix: ring 8, prefetch depth 7 -
// producer prologue issues 7 FILLs (63 loads = vmcnt HW cap), steady state
// FILL(k+7) + counted vmcnt(54) (6 FILLs in flight; tail cascade
// 45/36/27/18/9/0). Outstanding 27->63KB/block (~8MB total >> 2.4MB needed
// for HBM rate at ~900cy). LDS 134KB (1 block/CU already). Consumer
// identical to R20 (ring mask &7). Slot reuse safe: producer writes slot
// (k-1)&7 at iter k, fenced by consumer's lgkmcnt(0) before B(k).
// Gate: null again => per-wave gld_lds completion serialization; R22 =
// reg-staged producer (global_load_dwordx4 + ds_write_b128).
// Algorithm (validated R13-R20): fwd alpha <- f_t o (E alpha) t=0..255;
// bwd u <- E^T (f_t o u) t=511..256; out = ln2*(c2f+c2b+log2(dot(u,alpha))).

constexpr int SEQ = 512, BATCH = 1024, TAGS = 32;
constexpr int BPB = 8;               // batches per block
constexpr int CH = 8;                // steps per chunk
constexpr int NCH = (SEQ / 2) / CH;  // 32 chunks per direction
constexpr int RINGN = 8;             // ring depth (chunks)
constexpr int SSTRIDE = BPB * TAGS;  // step stride in LDS dwords (256)
constexpr int FSLOT = CH * SSTRIDE;  // feats dwords per chunk (2048)
constexpr int MSLOT = CH * BPB;      // mask dwords per chunk (64)

#define LOG2E 1.4426950408889634f
#define LN2   0.6931471805599453f

typedef __attribute__((ext_vector_type(8))) short short8;
typedef __attribute__((ext_vector_type(4))) float float4v;
union Frag8 { unsigned u[4]; short8 v; };

__device__ __forceinline__ unsigned pk_rn(float x, float y) {  // bf16 pack, x->low
  return __builtin_amdgcn_perm(__float_as_uint(y) + 0x8000u,
                               __float_as_uint(x) + 0x8000u, 0x07060302u);
}
__device__ __forceinline__ unsigned pk_tr(float x, float y) {  // trunc pack, x->low
  return __builtin_amdgcn_perm(__float_as_uint(y), __float_as_uint(x), 0x07060302u);
}

__device__ __forceinline__ void gld16(const float* g, float* l) {
  __builtin_amdgcn_global_load_lds((const __attribute__((address_space(1))) void*)g,
                                   (__attribute__((address_space(3))) void*)l, 16, 0, 0);
}
__device__ __forceinline__ void gld4(const float* g, float* l) {
  __builtin_amdgcn_global_load_lds((const __attribute__((address_space(1))) void*)g,
                                   (__attribute__((address_space(3))) void*)l, 4, 0, 0);
}

// ---------------- producer: stream chunks into the LDS ring ----------------
template <bool FWD>
__device__ __forceinline__ void produce(
    const float* __restrict__ feats, const float* __restrict__ maskp,
    float* __restrict__ FFd, float* __restrict__ MMd, int b0, int lane) {
  // feats: ONE gld16 per step (8 batches x 32 tags = 1 KB). LDS dword d of a
  // step slot holds feats[t][b0+(d>>5)][(d&31) ^ (((d>>5)&7)<<2)]
  // (pre-swizzled global source, linear LDS dest).
  const int bs = lane >> 3;                    // batch 0..7
  const int tg = 4 * ((lane & 7) ^ (bs & 7));  // swizzled tag group
  const size_t t0 = FWD ? 0 : (size_t)(SEQ - 1);
  const float* gF0 = feats + t0 * BATCH * TAGS + (size_t)(b0 + bs) * TAGS + tg;
  // mask: one gld4 per chunk (8 steps x 8 batches; lane l -> step l>>3,
  // batch l&7).
  const float* gM0 = maskp +
      (FWD ? (size_t)(lane >> 3) : (size_t)(SEQ - 1 - (lane >> 3))) * BATCH +
      b0 + (lane & 7);
  const ptrdiff_t fstep = FWD ? (ptrdiff_t)(BATCH * TAGS) : -(ptrdiff_t)(BATCH * TAGS);
  const ptrdiff_t mstep = FWD ? (ptrdiff_t)BATCH : -(ptrdiff_t)BATCH;

  auto FILL = [&](int k) {  // 9 vmcnt events per FILL
    float* fb = FFd + (k & (RINGN - 1)) * FSLOT;
    float* mb = MMd + (k & (RINGN - 1)) * MSLOT;
#pragma unroll
    for (int j = 0; j < CH; ++j)
      gld16(gF0 + (ptrdiff_t)(CH * k + j) * fstep, fb + j * SSTRIDE);
    gld4(gM0 + (ptrdiff_t)(CH * k) * mstep, mb);
  };

  FILL(0); FILL(1); FILL(2); FILL(3); FILL(4); FILL(5); FILL(6);  // 63 in flight
  asm volatile("s_waitcnt vmcnt(54)" ::: "memory");   // chunk 0 landed
  __builtin_amdgcn_s_barrier();                       // B0
  for (int k = 0; k < NCH; ++k) {
    if (k < NCH - 7) {
      FILL(k + 7);                                    // back to 63 in flight
      asm volatile("s_waitcnt vmcnt(54)" ::: "memory");  // chunk k+1 landed
    } else if (k == NCH - 7) {
      asm volatile("s_waitcnt vmcnt(45)" ::: "memory");
    } else if (k == NCH - 6) {
      asm volatile("s_waitcnt vmcnt(36)" ::: "memory");
    } else if (k == NCH - 5) {
      asm volatile("s_waitcnt vmcnt(27)" ::: "memory");
    } else if (k == NCH - 4) {
      asm volatile("s_waitcnt vmcnt(18)" ::: "memory");
    } else if (k == NCH - 3) {
      asm volatile("s_waitcnt vmcnt(9)" ::: "memory");
    } else if (k == NCH - 2) {
      asm volatile("s_waitcnt vmcnt(0)" ::: "memory");
    }
    __builtin_amdgcn_s_barrier();                     // B(k+1)
  }
  __syncthreads();  // junction barrier (match consumers)
}

// ---------------- consumer: run one direction's chain ----------------
template <bool FWD>
__device__ __forceinline__ void consume(
    const float* __restrict__ trans, float* __restrict__ out,
    const float* __restrict__ FFd, const float* __restrict__ MMd,
    float* __restrict__ vbuf, float* __restrict__ c2buf, int b0, int lane) {
  const int s = lane & 15, q = lane >> 4;
  // columns s>=8 carry garbage (don't-care): MFMA columns, per-column renorm,
  // and the junction dot are column-independent; output guard is lane<8.

  // sigma-permuted E fragments (A-operand layout: row=l&15, k in sig order
  // {4q..4q+3, 16+4q..16+4q+3} - verified R9-R20).
  int sig[8];
#pragma unroll
  for (int i = 0; i < 8; ++i) sig[i] = (i < 4) ? (4 * q + i) : (16 + 4 * q + (i - 4));
  Frag8 e0, e1;  // FWD: E rows (D=E*B). BWD: E^T rows.
#pragma unroll
  for (int p = 0; p < 4; ++p) {
    if (FWD) {
      e0.u[p] = pk_rn(__builtin_amdgcn_exp2f(trans[s * TAGS + sig[2 * p]] * LOG2E),
                      __builtin_amdgcn_exp2f(trans[s * TAGS + sig[2 * p + 1]] * LOG2E));
      e1.u[p] = pk_rn(__builtin_amdgcn_exp2f(trans[(16 + s) * TAGS + sig[2 * p]] * LOG2E),
                      __builtin_amdgcn_exp2f(trans[(16 + s) * TAGS + sig[2 * p + 1]] * LOG2E));
    } else {
      e0.u[p] = pk_rn(__builtin_amdgcn_exp2f(trans[sig[2 * p] * TAGS + s] * LOG2E),
                      __builtin_amdgcn_exp2f(trans[sig[2 * p + 1] * TAGS + s] * LOG2E));
      e1.u[p] = pk_rn(__builtin_amdgcn_exp2f(trans[sig[2 * p] * TAGS + 16 + s] * LOG2E),
                      __builtin_amdgcn_exp2f(trans[sig[2 * p + 1] * TAGS + 16 + s] * LOG2E));
    }
  }

  // state: a[i] = vec[j][b=s], j = sig-mapped.
  float a[8];
#pragma unroll
  for (int i = 0; i < 8; ++i) {
    if (FWD) a[i] = (q == 3 && i == 6) ? 1.0f : 0.0f;  // alpha0 = e_30
    else a[i] = __builtin_amdgcn_exp2f(
        trans[31 * TAGS + ((i < 4) ? (4 * q + i) : (16 + 4 * q + (i - 4)))] * LOG2E);
  }
  Frag8 Bf;
  Bf.u[0] = pk_tr(a[0], a[1]); Bf.u[1] = pk_tr(a[2], a[3]);
  Bf.u[2] = pk_tr(a[4], a[5]); Bf.u[3] = pk_tr(a[6], a[7]);
  float c2 = 0.f;
  const float4v zerov = {0.f, 0.f, 0.f, 0.f};

  // LDS read offsets (dwords within a step slot); valid for s<8.
  const int off0 = s * 32 + ((q ^ (s & 7)) << 2);
  const int off1 = s * 32 + (((q + 4) ^ (s & 7)) << 2);

  // register prefetch double-buffer: parity(j) holds r(j); Fc = exp'd F for
  // the CURRENT step (prepped one body ahead).
  float4v rA0, rA1, rB0, rB1;
  float mAv, mBv;
  float4v Fc0, Fc1;
  float mc;

  __builtin_amdgcn_s_barrier();  // B0: chunk 0 ready
  __builtin_amdgcn_sched_barrier(0);
  // prologue: slots 0,1 of chunk 0; Fc(0)
  rA0 = *(const float4v*)(FFd + 0 * SSTRIDE + off0);
  rA1 = *(const float4v*)(FFd + 0 * SSTRIDE + off1);
  mAv = MMd[0 * BPB + (s & 7)];
  rB0 = *(const float4v*)(FFd + 1 * SSTRIDE + off0);
  rB1 = *(const float4v*)(FFd + 1 * SSTRIDE + off1);
  mBv = MMd[1 * BPB + (s & 7)];
#pragma unroll
  for (int i = 0; i < 4; ++i) {
    Fc0[i] = __builtin_amdgcn_exp2f(rA0[i] * LOG2E);
    Fc1[i] = __builtin_amdgcn_exp2f(rA1[i] * LOG2E);
  }
  mc = mAv;

  for (int k = 0; k < NCH; ++k) {
    const float* fb = FFd + (k & (RINGN - 1)) * FSLOT;
    const float* mb = MMd + (k & (RINGN - 1)) * MSLOT;
#pragma unroll
    for (int j = 0; j < CH; ++j) {
      // prefetch step j+2 of this chunk into the parity-j buffer
      if (j < CH - 2) {
        float4v& c0 = (j & 1) ? rB0 : rA0;
        float4v& c1 = (j & 1) ? rB1 : rA1;
        float& cmv = (j & 1) ? mBv : mAv;
        c0 = *(const float4v*)(fb + (j + 2) * SSTRIDE + off0);
        c1 = *(const float4v*)(fb + (j + 2) * SSTRIDE + off1);
        cmv = mb[(j + 2) * BPB + (s & 7)];
      }

      // ---- step j: chain is MFMA -> mul/select -> pack only ----
      const bool mv = (mc != 0.0f);
      if (FWD) {
        // alpha' = F o (E alpha): D rows 4q+p == next B k-slots, same lane.
        const float4v D0 = __builtin_amdgcn_mfma_f32_16x16x32_bf16(e0.v, Bf.v, zerov, 0, 0, 0);
        const float4v D1 = __builtin_amdgcn_mfma_f32_16x16x32_bf16(e1.v, Bf.v, zerov, 0, 0, 0);
#pragma unroll
        for (int i = 0; i < 4; ++i) {
          a[i] = mv ? D0[i] * Fc0[i] : a[i];
          a[4 + i] = mv ? D1[i] * Fc1[i] : a[4 + i];
        }
      } else {
        // u' = E^T (F o u): mul before pack/MFMA.
        float tb[8];
#pragma unroll
        for (int i = 0; i < 4; ++i) { tb[i] = a[i] * Fc0[i]; tb[4 + i] = a[4 + i] * Fc1[i]; }
        Frag8 Bp;
        Bp.u[0] = pk_tr(tb[0], tb[1]); Bp.u[1] = pk_tr(tb[2], tb[3]);
        Bp.u[2] = pk_tr(tb[4], tb[5]); Bp.u[3] = pk_tr(tb[6], tb[7]);
        const float4v D0 = __builtin_amdgcn_mfma_f32_16x16x32_bf16(e0.v, Bp.v, zerov, 0, 0, 0);
        const float4v D1 = __builtin_amdgcn_mfma_f32_16x16x32_bf16(e1.v, Bp.v, zerov, 0, 0, 0);
#pragma unroll
        for (int i = 0; i < 4; ++i) {
          a[i] = mv ? D0[i] : a[i];
          a[4 + i] = mv ? D1[i] : a[4 + i];
        }
      }
      if (j == CH - 1) {  // renorm once per chunk (growth < 2^110)
        float mx = fmaxf(fmaxf(fmaxf(a[0], a[1]), fmaxf(a[2], a[3])),
                         fmaxf(fmaxf(a[4], a[5]), fmaxf(a[6], a[7])));
        mx = fmaxf(mx, __shfl_xor(mx, 16, 64));
        mx = fmaxf(mx, __shfl_xor(mx, 32, 64));
        const int ex = (int)((__float_as_uint(mx) >> 23) & 0xFFu) - 127;
        const float scl = __uint_as_float((unsigned)(127 - ex) << 23);  // exact 2^-ex
#pragma unroll
        for (int i = 0; i < 8; ++i) a[i] *= scl;
        c2 += (float)ex;
      }
      if (FWD) {
        Bf.u[0] = pk_tr(a[0], a[1]); Bf.u[1] = pk_tr(a[2], a[3]);
        Bf.u[2] = pk_tr(a[4], a[5]); Bf.u[3] = pk_tr(a[6], a[7]);
      }

      // prep Fc for step j+1 from the parity-(j+1) buffer (off the chain)
      if (j < CH - 1) {
        const float4v& n0 = (j & 1) ? rA0 : rB0;
        const float4v& n1 = (j & 1) ? rA1 : rB1;
        const float nm = (j & 1) ? mAv : mBv;
#pragma unroll
        for (int i = 0; i < 4; ++i) {
          Fc0[i] = __builtin_amdgcn_exp2f(n0[i] * LOG2E);
          Fc1[i] = __builtin_amdgcn_exp2f(n1[i] * LOG2E);
        }
        mc = nm;
      }
    }
    // reads of slot k retired before the producer may overwrite it (dist 7)
    asm volatile("s_waitcnt lgkmcnt(0)" ::: "memory");
    __builtin_amdgcn_s_barrier();  // B(k+1): chunk k+1 fully landed (producer)
    __builtin_amdgcn_sched_barrier(0);
    if (k < NCH - 1) {  // boundary prologue: slots 0,1 of chunk k+1; Fc(0)
      const float* fn = FFd + ((k + 1) & (RINGN - 1)) * FSLOT;
      const float* mn = MMd + ((k + 1) & (RINGN - 1)) * MSLOT;
      rA0 = *(const float4v*)(fn + 0 * SSTRIDE + off0);
      rA1 = *(const float4v*)(fn + 0 * SSTRIDE + off1);
      mAv = mn[0 * BPB + (s & 7)];
      rB0 = *(const float4v*)(fn + 1 * SSTRIDE + off0);
      rB1 = *(const float4v*)(fn + 1 * SSTRIDE + off1);
      mBv = mn[1 * BPB + (s & 7)];
#pragma unroll
      for (int i = 0; i < 4; ++i) {
        Fc0[i] = __builtin_amdgcn_exp2f(rA0[i] * LOG2E);
        Fc1[i] = __builtin_amdgcn_exp2f(rA1[i] * LOG2E);
      }
      mc = mAv;
    }
  }

  // ---- junction: out[b] = ln2 * (c2f + c2b + log2(dot(u, alpha)))
  if (!FWD) {
    float4v lo = {a[0], a[1], a[2], a[3]}, hi = {a[4], a[5], a[6], a[7]};
    *(float4v*)(vbuf + lane * 8) = lo;
    *(float4v*)(vbuf + lane * 8 + 4) = hi;
    if (lane < 8) c2buf[lane] = c2;
  }
  __syncthreads();  // junction barrier
  if (FWD) {
    const float4v v0 = *(const float4v*)(vbuf + lane * 8);
    const float4v v1 = *(const float4v*)(vbuf + lane * 8 + 4);
    float dot = a[0] * v0[0] + a[1] * v0[1] + a[2] * v0[2] + a[3] * v0[3] +
                a[4] * v1[0] + a[5] * v1[1] + a[6] * v1[2] + a[7] * v1[3];
    dot += __shfl_xor(dot, 16, 64);
    dot += __shfl_xor(dot, 32, 64);
    if (lane < 8)
      out[b0 + lane] = LN2 * (c2 + c2buf[lane] + __builtin_amdgcn_logf(dot));
  }
}

extern "C" __global__ void __launch_bounds__(256, 1) crf_scan(
    const float* __restrict__ feats, const float* __restrict__ mask,
    const float* __restrict__ trans, float* __restrict__ out) {
  __shared__ float FF[2][RINGN][FSLOT];  // 128 KB
  __shared__ float MM[2][RINGN][MSLOT];  // 4 KB
  __shared__ float vbuf[512];            // 2 KB
  __shared__ float c2buf[16];
  const int wid = threadIdx.x >> 6;
  const int lane = threadIdx.x & 63;
  const int b0 = blockIdx.x * BPB;  // 8 batches per block

  if (wid == 0)
    consume<true>(trans, out, &FF[0][0][0], &MM[0][0][0], vbuf, c2buf, b0, lane);
  else if (wid == 1)
    consume<false>(trans, out, &FF[1][0][0], &MM[1][0][0], vbuf, c2buf, b0, lane);
  else if (wid == 2)
    produce<true>(feats, mask, &FF[0][0][0], &MM[0][0][0], b0, lane);
  else
    produce<false>(feats, mask, &FF[1][0][0], &MM[1][0][0], b0, lane);
}

extern "C" void kernel_launch(void* const* d_in, const int* in_sizes, int n_in,
                              void* d_out, int out_size, void* d_ws, size_t ws_size,
                              hipStream_t stream) {
  const float* feats = (const float*)d_in[0];
  const float* mask  = (const float*)d_in[1];
  const float* trans = (const float*)d_in[2];
  float* out = (float*)d_out;
  hipLaunchKernelGGL(crf_scan, dim3(BATCH / BPB), dim3(256), 0, stream,
                     feats, mask, trans, out);
}

// Round 13
// 106.883 us; speedup vs baseline: 1.1216x; 1.1216x over previous
//
#include <hip/hip_runtime.h>

// CRF forward (log-partition), SEQ=512, BATCH=1024, TAGS=32, fp32 in/out.
//
// R22: strip the consumer's serial chain. Evidence: R20 replay dispatches
// with 4 KB HBM traffic still took 41.7us -> execution-bound, not delivery;
// VALUBusy back-solve gives ~230 cy/step, matching the step audit: 8 exp2
// (quarter-rate, 64cy) + 16 mul/cndmask + packs + renorm + skew. R17-R21
// delivery work was null because the consumer issue stream was the floor,
// while producers idled ~90% of each chunk.
// Changes:
//  1. Producers reg-stage (global_load_dwordx4, depth-2 chunk pipeline),
//     compute exp2 THERE (32/lane/chunk fits their slack), ds_write_b128
//     the exp'd f32 F into LDS - swizzle applied at the per-lane write.
//  2. Producer publishes a per-chunk all-ones mask flag (ballot); consumer
//     branches (scalar): fast body without cndmask selects; masked
//     fallback for correctness.
//  3. Consumer step = 2 ds_read (2 ahead) + 2 MFMA + 8 mul + 4 pack.
//  4. Ring 2 (producer is reg-pipeline limited), LDS 137->34 KB.
// Gate: if dispatch >=38us, ~41us is an environmental floor -> roofline.
// Algorithm (validated R13-R21): fwd alpha <- f_t o (E alpha) t=0..255;
// bwd u <- E^T (f_t o u) t=511..256; out = ln2*(c2f+c2b+log2(dot(u,alpha))).

constexpr int SEQ = 512, BATCH = 1024, TAGS = 32;
constexpr int BPB = 8;               // batches per block
constexpr int CH = 8;                // steps per chunk
constexpr int NCH = (SEQ / 2) / CH;  // 32 chunks per direction
constexpr int RINGN = 2;             // ring depth (chunks)
constexpr int SSTRIDE = BPB * TAGS;  // step stride in LDS dwords (256)
constexpr int FSLOT = CH * SSTRIDE;  // dwords per chunk slot (2048)
constexpr int MSLOT = CH * BPB;      // mask dwords per chunk (64)

#define LOG2E 1.4426950408889634f
#define LN2   0.6931471805599453f

typedef __attribute__((ext_vector_type(8))) short short8;
typedef __attribute__((ext_vector_type(4))) float float4v;
union Frag8 { unsigned u[4]; short8 v; };

__device__ __forceinline__ unsigned pk_rn(float x, float y) {  // bf16 pack, x->low
  return __builtin_amdgcn_perm(__float_as_uint(y) + 0x8000u,
                               __float_as_uint(x) + 0x8000u, 0x07060302u);
}
__device__ __forceinline__ unsigned pk_tr(float x, float y) {  // trunc pack, x->low
  return __builtin_amdgcn_perm(__float_as_uint(y), __float_as_uint(x), 0x07060302u);
}

// ---------------- producer: load -> exp2 -> swizzled ds_write ----------------
template <bool FWD>
__device__ __forceinline__ void produce(
    const float* __restrict__ feats, const float* __restrict__ maskp,
    float* __restrict__ FFd, float* __restrict__ MMd,
    unsigned* __restrict__ FLGd, int b0, int lane) {
  const int bl = lane >> 3;        // batch 0..7
  const int tgd = (lane & 7) * 4;  // tag-group dword offset
  const size_t t0off = FWD ? 0 : (size_t)(SEQ - 1) * BATCH * TAGS;
  const float* gF = feats + t0off + (size_t)(b0 + bl) * TAGS + tgd;
  const float* gM = maskp + b0 + (lane & 7) + (FWD ? 0 : (size_t)(SEQ - 1) * BATCH);
  const ptrdiff_t fstep = FWD ? (ptrdiff_t)(BATCH * TAGS) : -(ptrdiff_t)(BATCH * TAGS);
  const ptrdiff_t mstep = FWD ? (ptrdiff_t)BATCH : -(ptrdiff_t)BATCH;
  // swizzled write slot: loc b*32 + (g^(b&7))*4 holds tag-group g of batch b
  const int wd = bl * 32 + (((lane & 7) ^ (bl & 7)) << 2);

  float4v SA[CH], SB[CH];  // raw feats for one chunk each (depth-2 pipeline)
  float mA, mB;

#define LOADC(S, MV, c)                                                       \
  { _Pragma("unroll") for (int j = 0; j < CH; ++j)                            \
      S[j] = *(const float4v*)(gF + (ptrdiff_t)(CH * (c) + j) * fstep);       \
    MV = gM[(ptrdiff_t)(CH * (c) + (lane >> 3)) * mstep]; }

#define PROC(S, MV, c)                                                        \
  { float* fb = FFd + ((c) & (RINGN - 1)) * FSLOT;                            \
    float* mb = MMd + ((c) & (RINGN - 1)) * MSLOT;                            \
    const unsigned flag = (__ballot(MV != 0.0f) == ~0ull) ? 1u : 0u;          \
    _Pragma("unroll") for (int j = 0; j < CH; ++j) {                          \
      float4v e;                                                              \
      _Pragma("unroll") for (int i = 0; i < 4; ++i)                           \
        e[i] = __builtin_amdgcn_exp2f(S[j][i] * LOG2E);                       \
      *(float4v*)(fb + j * SSTRIDE + wd) = e;                                 \
    }                                                                         \
    mb[lane] = MV;                                                            \
    if (lane == 0) FLGd[(c) & (RINGN - 1)] = flag; }

  LOADC(SA, mA, 0)
  LOADC(SB, mB, 1)
  PROC(SA, mA, 0)
  asm volatile("s_waitcnt lgkmcnt(0)" ::: "memory");
  __builtin_amdgcn_s_barrier();  // B0: chunk 0 ready
#pragma unroll 2
  for (int k = 0; k < NCH; ++k) {
    // refill the set that held chunk k (consumed last iter) with chunk k+2,
    // then exp+write chunk k+1 (loaded last iter; ~1 chunk period in flight).
    if ((k & 1) == 0) {
      if (k + 2 < NCH) LOADC(SA, mA, k + 2)
      if (k + 1 < NCH) PROC(SB, mB, k + 1)
    } else {
      if (k + 2 < NCH) LOADC(SB, mB, k + 2)
      if (k + 1 < NCH) PROC(SA, mA, k + 1)
    }
    asm volatile("s_waitcnt lgkmcnt(0)" ::: "memory");
    __builtin_amdgcn_s_barrier();  // B(k+1): chunk k+1 ready
  }
  __syncthreads();  // junction barrier (match consumers)
#undef LOADC
#undef PROC
}

// ---------------- consumer: run one direction's chain ----------------
template <bool FWD>
__device__ __forceinline__ void consume(
    const float* __restrict__ trans, float* __restrict__ out,
    const float* __restrict__ FFd, const float* __restrict__ MMd,
    const unsigned* __restrict__ FLGd,
    float* __restrict__ vbuf, float* __restrict__ c2buf, int b0, int lane) {
  const int s = lane & 15, q = lane >> 4;
  // columns s>=8 carry garbage (don't-care; over-reads stay inside FF+MM).

  // sigma-permuted E fragments (A-operand layout: row=l&15, k in sig order
  // {4q..4q+3, 16+4q..16+4q+3} - verified R9-R21).
  int sig[8];
#pragma unroll
  for (int i = 0; i < 8; ++i) sig[i] = (i < 4) ? (4 * q + i) : (16 + 4 * q + (i - 4));
  Frag8 e0, e1;  // FWD: E rows (D=E*B). BWD: E^T rows.
#pragma unroll
  for (int p = 0; p < 4; ++p) {
    if (FWD) {
      e0.u[p] = pk_rn(__builtin_amdgcn_exp2f(trans[s * TAGS + sig[2 * p]] * LOG2E),
                      __builtin_amdgcn_exp2f(trans[s * TAGS + sig[2 * p + 1]] * LOG2E));
      e1.u[p] = pk_rn(__builtin_amdgcn_exp2f(trans[(16 + s) * TAGS + sig[2 * p]] * LOG2E),
                      __builtin_amdgcn_exp2f(trans[(16 + s) * TAGS + sig[2 * p + 1]] * LOG2E));
    } else {
      e0.u[p] = pk_rn(__builtin_amdgcn_exp2f(trans[sig[2 * p] * TAGS + s] * LOG2E),
                      __builtin_amdgcn_exp2f(trans[sig[2 * p + 1] * TAGS + s] * LOG2E));
      e1.u[p] = pk_rn(__builtin_amdgcn_exp2f(trans[sig[2 * p] * TAGS + 16 + s] * LOG2E),
                      __builtin_amdgcn_exp2f(trans[sig[2 * p + 1] * TAGS + 16 + s] * LOG2E));
    }
  }

  // state: a[i] = vec[j][b=s], j = sig-mapped.
  float a[8];
#pragma unroll
  for (int i = 0; i < 8; ++i) {
    if (FWD) a[i] = (q == 3 && i == 6) ? 1.0f : 0.0f;  // alpha0 = e_30
    else a[i] = __builtin_amdgcn_exp2f(
        trans[31 * TAGS + ((i < 4) ? (4 * q + i) : (16 + 4 * q + (i - 4)))] * LOG2E);
  }
  Frag8 Bf;
  Bf.u[0] = pk_tr(a[0], a[1]); Bf.u[1] = pk_tr(a[2], a[3]);
  Bf.u[2] = pk_tr(a[4], a[5]); Bf.u[3] = pk_tr(a[6], a[7]);
  float c2 = 0.f;
  const float4v zerov = {0.f, 0.f, 0.f, 0.f};

  // LDS read offsets (dwords within a step slot); <=2-way bank aliasing.
  const int off0 = s * 32 + ((q ^ (s & 7)) << 2);
  const int off1 = s * 32 + (((q + 4) ^ (s & 7)) << 2);

  // Fc register prefetch (2 steps ahead): parity(j) buffer holds F(j) (exp'd).
  float4v rA0, rA1, rB0, rB1;

  __builtin_amdgcn_s_barrier();  // B0: chunk 0 ready
  __builtin_amdgcn_sched_barrier(0);
  rA0 = *(const float4v*)(FFd + 0 * SSTRIDE + off0);
  rA1 = *(const float4v*)(FFd + 0 * SSTRIDE + off1);
  rB0 = *(const float4v*)(FFd + 1 * SSTRIDE + off0);
  rB1 = *(const float4v*)(FFd + 1 * SSTRIDE + off1);

#define RENORM_A()                                                            \
  { float mx = fmaxf(fmaxf(fmaxf(a[0], a[1]), fmaxf(a[2], a[3])),             \
                     fmaxf(fmaxf(a[4], a[5]), fmaxf(a[6], a[7])));            \
    mx = fmaxf(mx, __shfl_xor(mx, 16, 64));                                   \
    mx = fmaxf(mx, __shfl_xor(mx, 32, 64));                                   \
    const int ex = (int)((__float_as_uint(mx) >> 23) & 0xFFu) - 127;          \
    const float scl = __uint_as_float((unsigned)(127 - ex) << 23);            \
    _Pragma("unroll") for (int i = 0; i < 8; ++i) a[i] *= scl;                \
    c2 += (float)ex; }

  for (int k = 0; k < NCH; ++k) {
    const float* fb = FFd + (k & (RINGN - 1)) * FSLOT;
    const float* mb = MMd + (k & (RINGN - 1)) * MSLOT;
    const unsigned fl = __builtin_amdgcn_readfirstlane(FLGd[k & (RINGN - 1)]);
    if (fl) {  // -------- fast path: all masks set, no selects --------
#pragma unroll
      for (int j = 0; j < CH; ++j) {
        const float4v F0 = (j & 1) ? rB0 : rA0;
        const float4v F1 = (j & 1) ? rB1 : rA1;
        if (FWD) {
          const float4v D0 = __builtin_amdgcn_mfma_f32_16x16x32_bf16(e0.v, Bf.v, zerov, 0, 0, 0);
          const float4v D1 = __builtin_amdgcn_mfma_f32_16x16x32_bf16(e1.v, Bf.v, zerov, 0, 0, 0);
#pragma unroll
          for (int i = 0; i < 4; ++i) { a[i] = D0[i] * F0[i]; a[4 + i] = D1[i] * F1[i]; }
          if (j == CH - 1) RENORM_A()
          Bf.u[0] = pk_tr(a[0], a[1]); Bf.u[1] = pk_tr(a[2], a[3]);
          Bf.u[2] = pk_tr(a[4], a[5]); Bf.u[3] = pk_tr(a[6], a[7]);
        } else {
          float tb[8];
#pragma unroll
          for (int i = 0; i < 4; ++i) { tb[i] = a[i] * F0[i]; tb[4 + i] = a[4 + i] * F1[i]; }
          Frag8 Bp;
          Bp.u[0] = pk_tr(tb[0], tb[1]); Bp.u[1] = pk_tr(tb[2], tb[3]);
          Bp.u[2] = pk_tr(tb[4], tb[5]); Bp.u[3] = pk_tr(tb[6], tb[7]);
          const float4v D0 = __builtin_amdgcn_mfma_f32_16x16x32_bf16(e0.v, Bp.v, zerov, 0, 0, 0);
          const float4v D1 = __builtin_amdgcn_mfma_f32_16x16x32_bf16(e1.v, Bp.v, zerov, 0, 0, 0);
#pragma unroll
          for (int i = 0; i < 4; ++i) { a[i] = D0[i]; a[4 + i] = D1[i]; }
          if (j == CH - 1) RENORM_A()
        }
        // prefetch F(j+2) into the parity-j buffer (after use; in-order WAR safe)
        if (j < CH - 2) {
          ((j & 1) ? rB0 : rA0) = *(const float4v*)(fb + (j + 2) * SSTRIDE + off0);
          ((j & 1) ? rB1 : rA1) = *(const float4v*)(fb + (j + 2) * SSTRIDE + off1);
        }
      }
    } else {  // -------- masked path (rare): per-column selects --------
#pragma unroll
      for (int j = 0; j < CH; ++j) {
        const float4v F0 = (j & 1) ? rB0 : rA0;
        const float4v F1 = (j & 1) ? rB1 : rA1;
        const bool mv = (mb[j * BPB + (s & 7)] != 0.0f);
        if (FWD) {
          const float4v D0 = __builtin_amdgcn_mfma_f32_16x16x32_bf16(e0.v, Bf.v, zerov, 0, 0, 0);
          const float4v D1 = __builtin_amdgcn_mfma_f32_16x16x32_bf16(e1.v, Bf.v, zerov, 0, 0, 0);
#pragma unroll
          for (int i = 0; i < 4; ++i) {
            a[i] = mv ? D0[i] * F0[i] : a[i];
            a[4 + i] = mv ? D1[i] * F1[i] : a[4 + i];
          }
          if (j == CH - 1) RENORM_A()
          Bf.u[0] = pk_tr(a[0], a[1]); Bf.u[1] = pk_tr(a[2], a[3]);
          Bf.u[2] = pk_tr(a[4], a[5]); Bf.u[3] = pk_tr(a[6], a[7]);
        } else {
          float tb[8];
#pragma unroll
          for (int i = 0; i < 4; ++i) { tb[i] = a[i] * F0[i]; tb[4 + i] = a[4 + i] * F1[i]; }
          Frag8 Bp;
          Bp.u[0] = pk_tr(tb[0], tb[1]); Bp.u[1] = pk_tr(tb[2], tb[3]);
          Bp.u[2] = pk_tr(tb[4], tb[5]); Bp.u[3] = pk_tr(tb[6], tb[7]);
          const float4v D0 = __builtin_amdgcn_mfma_f32_16x16x32_bf16(e0.v, Bp.v, zerov, 0, 0, 0);
          const float4v D1 = __builtin_amdgcn_mfma_f32_16x16x32_bf16(e1.v, Bp.v, zerov, 0, 0, 0);
#pragma unroll
          for (int i = 0; i < 4; ++i) {
            a[i] = mv ? D0[i] : a[i];
            a[4 + i] = mv ? D1[i] : a[4 + i];
          }
          if (j == CH - 1) RENORM_A()
        }
        if (j < CH - 2) {
          ((j & 1) ? rB0 : rA0) = *(const float4v*)(fb + (j + 2) * SSTRIDE + off0);
          ((j & 1) ? rB1 : rA1) = *(const float4v*)(fb + (j + 2) * SSTRIDE + off1);
        }
      }
    }
    // reads of slot k retired before producer overwrites it next window
    asm volatile("s_waitcnt lgkmcnt(0)" ::: "memory");
    __builtin_amdgcn_s_barrier();  // B(k+1): chunk k+1 ready
    __builtin_amdgcn_sched_barrier(0);
    if (k < NCH - 1) {  // boundary prologue: F(0),F(1) of chunk k+1
      const float* fn = FFd + ((k + 1) & (RINGN - 1)) * FSLOT;
      rA0 = *(const float4v*)(fn + 0 * SSTRIDE + off0);
      rA1 = *(const float4v*)(fn + 0 * SSTRIDE + off1);
      rB0 = *(const float4v*)(fn + 1 * SSTRIDE + off0);
      rB1 = *(const float4v*)(fn + 1 * SSTRIDE + off1);
    }
  }
#undef RENORM_A

  // ---- junction: out[b] = ln2 * (c2f + c2b + log2(dot(u, alpha)))
  if (!FWD) {
    float4v lo = {a[0], a[1], a[2], a[3]}, hi = {a[4], a[5], a[6], a[7]};
    *(float4v*)(vbuf + lane * 8) = lo;
    *(float4v*)(vbuf + lane * 8 + 4) = hi;
    if (lane < 8) c2buf[lane] = c2;
  }
  __syncthreads();  // junction barrier
  if (FWD) {
    const float4v v0 = *(const float4v*)(vbuf + lane * 8);
    const float4v v1 = *(const float4v*)(vbuf + lane * 8 + 4);
    float dot = a[0] * v0[0] + a[1] * v0[1] + a[2] * v0[2] + a[3] * v0[3] +
                a[4] * v1[0] + a[5] * v1[1] + a[6] * v1[2] + a[7] * v1[3];
    dot += __shfl_xor(dot, 16, 64);
    dot += __shfl_xor(dot, 32, 64);
    if (lane < 8)
      out[b0 + lane] = LN2 * (c2 + c2buf[lane] + __builtin_amdgcn_logf(dot));
  }
}

extern "C" __global__ void __launch_bounds__(256, 1) crf_scan(
    const float* __restrict__ feats, const float* __restrict__ mask,
    const float* __restrict__ trans, float* __restrict__ out) {
  // NOTE: order matters - consumer garbage-column over-reads (s>=8, j=7) run
  // up to 255 dwords past FF and must land in MM (in-bounds don't-care).
  __shared__ float FF[2][RINGN][FSLOT];   // 32 KB (exp'd F, swizzled)
  __shared__ float MM[2][RINGN][MSLOT];   // 1 KB
  __shared__ unsigned FLG[2][RINGN];
  __shared__ float vbuf[512];             // 2 KB
  __shared__ float c2buf[16];
  const int wid = threadIdx.x >> 6;
  const int lane = threadIdx.x & 63;
  const int b0 = blockIdx.x * BPB;  // 8 batches per block

  if (wid == 0)
    consume<true>(trans, out, &FF[0][0][0], &MM[0][0][0], &FLG[0][0], vbuf, c2buf, b0, lane);
  else if (wid == 1)
    consume<false>(trans, out, &FF[1][0][0], &MM[1][0][0], &FLG[1][0], vbuf, c2buf, b0, lane);
  else if (wid == 2)
    produce<true>(feats, mask, &FF[0][0][0], &MM[0][0][0], &FLG[0][0], b0, lane);
  else
    produce<false>(feats, mask, &FF[1][0][0], &MM[1][0][0], &FLG[1][0], b0, lane);
}

extern "C" void kernel_launch(void* const* d_in, const int* in_sizes, int n_in,
                              void* d_out, int out_size, void* d_ws, size_t ws_size,
                              hipStream_t stream) {
  const float* feats = (const float*)d_in[0];
  const float* mask  = (const float*)d_in[1];
  const float* trans = (const float*)d_in[2];
  float* out = (float*)d_out;
  hipLaunchKernelGGL(crf_scan, dim3(BATCH / BPB), dim3(256), 0, stream,
                     feats, mask, trans, out);
}